// Round 7
// baseline (1400.393 us; speedup 1.0000x reference)
//
#include <hip/hip_runtime.h>
#include <hip/hip_fp16.h>
#include <math.h>

#define NF 128
#define NC 40

typedef unsigned short bfraw;
typedef float f32x4 __attribute__((ext_vector_type(4)));

__device__ __forceinline__ float bfLo(unsigned u) {
  return __uint_as_float(u << 16);
}
__device__ __forceinline__ float bfHi(unsigned u) {
  return __uint_as_float(u & 0xffff0000u);
}
__device__ __forceinline__ unsigned short f2bf(float f) {
  unsigned u = __float_as_uint(f);
  u += 0x7fff + ((u >> 16) & 1);  // RNE
  return (unsigned short)(u >> 16);
}
// weight in [0,1): positive fp16, 15 bits (no sign)
__device__ __forceinline__ unsigned short f2h15(float f) {
  __half h = __float2half(f);
  __half_raw hr = static_cast<__half_raw>(h);
  return (unsigned short)(hr.x & 0x7FFF);
}
__device__ __forceinline__ float h15tof(unsigned rec) {
  __half_raw hr;
  hr.x = (unsigned short)(rec & 0x7FFF);
  __half h = static_cast<__half>(hr);
  return __half2float(h);
}

// ---------------- CSR build ----------------

__global__ __launch_bounds__(256) void count_kernel(const int* __restrict__ tgt,
                                                    int* __restrict__ cnt, int e) {
  int i = blockIdx.x * 256 + threadIdx.x;
  if (i < e) atomicAdd(&cnt[__builtin_nontemporal_load(&tgt[i])], 1);
}

__global__ __launch_bounds__(1024) void scan1_kernel(const int* __restrict__ cnt,
                                                     int* __restrict__ rp,
                                                     int* __restrict__ bsum, int n) {
  __shared__ int wsum[16];
  int tid = threadIdx.x, lane = tid & 63, wid = tid >> 6;
  int i = blockIdx.x * 1024 + tid;
  int v = (i < n) ? cnt[i] : 0;
  int x = v;
  #pragma unroll
  for (int off = 1; off < 64; off <<= 1) {
    int t = __shfl_up(x, off);
    if (lane >= off) x += t;
  }
  if (lane == 63) wsum[wid] = x;
  __syncthreads();
  if (wid == 0) {
    int ws = (lane < 16) ? wsum[lane] : 0;
    int y = ws;
    #pragma unroll
    for (int off = 1; off < 16; off <<= 1) {
      int t = __shfl_up(y, off);
      if (lane >= off) y += t;
    }
    if (lane < 16) wsum[lane] = y - ws;
  }
  __syncthreads();
  int incl = x + wsum[wid];
  if (i < n) rp[i] = incl - v;
  if (tid == 1023) bsum[blockIdx.x] = incl;
}

__global__ __launch_bounds__(1024) void scan2_kernel(int* __restrict__ bsum, int nb,
                                                     int* __restrict__ rp_n) {
  __shared__ int wsum[16];
  int tid = threadIdx.x, lane = tid & 63, wid = tid >> 6;
  int v = (tid < nb) ? bsum[tid] : 0;
  int x = v;
  #pragma unroll
  for (int off = 1; off < 64; off <<= 1) {
    int t = __shfl_up(x, off);
    if (lane >= off) x += t;
  }
  if (lane == 63) wsum[wid] = x;
  __syncthreads();
  if (wid == 0) {
    int ws = (lane < 16) ? wsum[lane] : 0;
    int y = ws;
    #pragma unroll
    for (int off = 1; off < 16; off <<= 1) {
      int t = __shfl_up(y, off);
      if (lane >= off) y += t;
    }
    if (lane < 16) wsum[lane] = y - ws;
  }
  __syncthreads();
  int incl = x + wsum[wid];
  if (tid < nb) bsum[tid] = incl - v;
  if (tid == 1023) *rp_n = incl;
}

__global__ __launch_bounds__(256) void scan3_kernel(int* __restrict__ rp,
                                                    int* __restrict__ cursor,
                                                    const int* __restrict__ bsum, int n) {
  int i = blockIdx.x * 256 + threadIdx.x;
  if (i < n) {
    int v = rp[i] + bsum[i >> 10];
    rp[i] = v;
    cursor[i] = v;
  }
}

// XCD-partitioned scatter; streaming reads non-temporal.
__global__ __launch_bounds__(256) void fill_kernel(const int* __restrict__ src,
                                                   const int* __restrict__ tgt,
                                                   const float* __restrict__ mw,
                                                   int* __restrict__ cursor,
                                                   unsigned* __restrict__ ecsr,
                                                   int e, int n) {
  int part = blockIdx.x & 7;
  int nset = gridDim.x >> 3;
  int lo = (int)(((long long)n * part) >> 3);
  int hi = (int)(((long long)n * (part + 1)) >> 3);
  int stride = nset * 256;
  for (int i = (blockIdx.x >> 3) * 256 + threadIdx.x; i < e; i += stride) {
    int t = __builtin_nontemporal_load(&tgt[i]);
    if (t >= lo && t < hi) {
      int pos = atomicAdd(&cursor[t], 1);
      unsigned s = (unsigned)__builtin_nontemporal_load(&src[i]);
      float w = __builtin_nontemporal_load(&mw[i]);
      ecsr[pos] = (s << 15) | f2h15(w);
    }
  }
}

// ---------------- GEMM: Tblk[8][n][16](bf16) = X[N,128] @ W[128,128] ----------------
// output written in feature-blocked layout for the L2-resident gather.

__global__ __launch_bounds__(256) void gemm128_kernel(const float* __restrict__ X,
                                                      const float* __restrict__ W,
                                                      bfraw* __restrict__ Tb, int n) {
  __shared__ float Xs[64][NF];
  int block_row = blockIdx.x * 64;
  int tid = threadIdx.x;
  #pragma unroll
  for (int it = 0; it < 8; ++it) {
    int flat = it * 1024 + tid * 4;
    int r = flat >> 7, c = flat & 127;
    int gr = block_row + r;
    float4 v = make_float4(0.f, 0.f, 0.f, 0.f);
    if (gr < n) v = *(const float4*)&X[(size_t)gr * NF + c];
    *(float4*)&Xs[r][c] = v;
  }
  __syncthreads();
  int cg = tid & 31;
  int rg = tid >> 5;
  float4 acc[8];
  #pragma unroll
  for (int r = 0; r < 8; ++r) acc[r] = make_float4(0.f, 0.f, 0.f, 0.f);
  for (int k = 0; k < NF; ++k) {
    float4 w = *(const float4*)&W[k * NF + cg * 4];
    #pragma unroll
    for (int r = 0; r < 8; ++r) {
      float xv = Xs[rg * 8 + r][k];
      acc[r].x += xv * w.x;
      acc[r].y += xv * w.y;
      acc[r].z += xv * w.z;
      acc[r].w += xv * w.w;
    }
  }
  int fb = cg >> 2;          // feature block 0..7
  int co = (cg & 3) * 4;     // offset within 16-feature block
  #pragma unroll
  for (int r = 0; r < 8; ++r) {
    int gr = block_row + rg * 8 + r;
    if (gr < n) {
      ushort4 o;
      o.x = f2bf(acc[r].x); o.y = f2bf(acc[r].y);
      o.z = f2bf(acc[r].z); o.w = f2bf(acc[r].w);
      *(ushort4*)&Tb[((size_t)fb * n + gr) * 16 + co] = o;
    }
  }
}

// ---------------- aggregation (pull), feature-blocked, L2-resident ----------------
// grid = 8 * ceil(n/4) blocks; fb = blockIdx & 7 pins each feature block to one
// XCD (round-robin dispatch): its 3.2 MB slice of Tblk stays in the 4 MB L2.
// wave = 1 node x 16 features: 16 edge slots x 4 lanes (8 B each).

template <bool RELU, bool RES, bool BIAS, bool OUTBF>
__global__ __launch_bounds__(256) void agg128_kernel(const bfraw* __restrict__ Tblk,
                                                     const int* __restrict__ rp,
                                                     const unsigned* __restrict__ ecsr,
                                                     const float* __restrict__ bias,
                                                     const float* __restrict__ Hres,
                                                     void* __restrict__ HoutV, int n) {
  int fb = blockIdx.x & 7;
  int node = (blockIdx.x >> 3) * 4 + (threadIdx.x >> 6);
  int lane = threadIdx.x & 63;
  if (node >= n) return;
  int eq = lane >> 2;  // edge slot 0..15
  int fq = lane & 3;   // feature quad: feats fb*16 + fq*4 .. +3
  int beg = rp[node], end = rp[node + 1];
  float a0 = 0.f, a1 = 0.f, a2 = 0.f, a3 = 0.f;
  const bfraw* base = Tblk + (size_t)fb * n * 16 + fq * 4;
  for (int eidx = beg + eq; eidx < end; eidx += 16) {
    unsigned rec = __builtin_nontemporal_load(&ecsr[eidx]);
    float w = h15tof(rec);
    uint2 q = *(const uint2*)(base + (size_t)(rec >> 15) * 16);  // cacheable: resident slice
    a0 = fmaf(w, bfLo(q.x), a0);
    a1 = fmaf(w, bfHi(q.x), a1);
    a2 = fmaf(w, bfLo(q.y), a2);
    a3 = fmaf(w, bfHi(q.y), a3);
  }
  #pragma unroll
  for (int off = 4; off < 64; off <<= 1) {
    a0 += __shfl_xor(a0, off);
    a1 += __shfl_xor(a1, off);
    a2 += __shfl_xor(a2, off);
    a3 += __shfl_xor(a3, off);
  }
  if (eq == 0) {
    int fbase = fb * 16 + fq * 4;
    if (BIAS) {
      float4 b = *(const float4*)&bias[fbase];
      a0 += b.x; a1 += b.y; a2 += b.z; a3 += b.w;
    }
    if (RELU) {
      a0 = fmaxf(a0, 0.f); a1 = fmaxf(a1, 0.f);
      a2 = fmaxf(a2, 0.f); a3 = fmaxf(a3, 0.f);
    }
    if (RES) {
      f32x4 r = __builtin_nontemporal_load(
          (const f32x4*)&Hres[(size_t)node * NF + fbase]);
      a0 += r.x; a1 += r.y; a2 += r.z; a3 += r.w;
    }
    if (OUTBF) {
      // blocked bf16 output (consumed by the next blocked gather)
      bfraw* Hout = (bfraw*)HoutV;
      uint2 o;
      o.x = ((unsigned)f2bf(a1) << 16) | f2bf(a0);
      o.y = ((unsigned)f2bf(a3) << 16) | f2bf(a2);
      __builtin_nontemporal_store(o.x, (unsigned*)&Hout[((size_t)fb * n + node) * 16 + fq * 4]);
      __builtin_nontemporal_store(o.y, (unsigned*)&Hout[((size_t)fb * n + node) * 16 + fq * 4 + 2]);
    } else {
      float* Hout = (float*)HoutV;
      f32x4 o;
      o.x = a0; o.y = a1; o.z = a2; o.w = a3;
      __builtin_nontemporal_store(o, (f32x4*)&Hout[(size_t)node * NF + fbase]);
    }
  }
}

// ---------------- fused final: out = log_softmax(A@W3 + b3) ----------------

__global__ __launch_bounds__(256) void gemm40_lsm_kernel(const float* __restrict__ A,
                                                         const float* __restrict__ W,
                                                         const float* __restrict__ bias,
                                                         float* __restrict__ out, int n) {
  __shared__ float Ws[NF * NC];  // 20 KB
  int tid = threadIdx.x;
  #pragma unroll
  for (int it = 0; it < 5; ++it) {
    int off = it * 1024 + tid * 4;
    *(float4*)&Ws[off] = *(const float4*)&W[off];
  }
  __syncthreads();
  int node = blockIdx.x * 256 + tid;
  if (node >= n) return;

  float4 acc[10];
  #pragma unroll
  for (int cg = 0; cg < 10; ++cg) acc[cg] = *(const float4*)&bias[cg * 4];

  const float* arow = A + (size_t)node * NF;
  for (int k0 = 0; k0 < NF; k0 += 4) {
    float4 a4 = *(const float4*)&arow[k0];
    float av[4] = {a4.x, a4.y, a4.z, a4.w};
    #pragma unroll
    for (int j = 0; j < 4; ++j) {
      #pragma unroll
      for (int cg = 0; cg < 10; ++cg) {
        float4 w4 = *(const float4*)&Ws[(k0 + j) * NC + cg * 4];
        acc[cg].x = fmaf(av[j], w4.x, acc[cg].x);
        acc[cg].y = fmaf(av[j], w4.y, acc[cg].y);
        acc[cg].z = fmaf(av[j], w4.z, acc[cg].z);
        acc[cg].w = fmaf(av[j], w4.w, acc[cg].w);
      }
    }
  }
  float m = -INFINITY;
  #pragma unroll
  for (int cg = 0; cg < 10; ++cg) {
    m = fmaxf(m, fmaxf(fmaxf(acc[cg].x, acc[cg].y), fmaxf(acc[cg].z, acc[cg].w)));
  }
  float s = 0.f;
  #pragma unroll
  for (int cg = 0; cg < 10; ++cg) {
    s += expf(acc[cg].x - m) + expf(acc[cg].y - m) +
         expf(acc[cg].z - m) + expf(acc[cg].w - m);
  }
  float lse = m + logf(s);
  float* orow = out + (size_t)node * NC;
  #pragma unroll
  for (int cg = 0; cg < 10; ++cg) {
    float4 o;
    o.x = acc[cg].x - lse; o.y = acc[cg].y - lse;
    o.z = acc[cg].z - lse; o.w = acc[cg].w - lse;
    *(float4*)&orow[cg * 4] = o;
  }
}

// ---------------- launch ----------------

extern "C" void kernel_launch(void* const* d_in, const int* in_sizes, int n_in,
                              void* d_out, int out_size, void* d_ws, size_t ws_size,
                              hipStream_t stream) {
  const float* x   = (const float*)d_in[0];
  const int*   src = (const int*)d_in[1];
  const int*   tgt = (const int*)d_in[2];
  const float* mw  = (const float*)d_in[3];
  const float* W0  = (const float*)d_in[4];
  const float* b0  = (const float*)d_in[5];
  const float* W1  = (const float*)d_in[6];
  const float* b1  = (const float*)d_in[7];
  const float* W2  = (const float*)d_in[8];
  const float* b2  = (const float*)d_in[9];
  const float* W3  = (const float*)d_in[10];
  const float* b3  = (const float*)d_in[11];
  int n = in_sizes[0] / NF;
  int e = in_sizes[1];
  float* out = (float*)d_out;

  char* ws = (char*)d_ws;
  size_t nbF = (size_t)n * NF * sizeof(float);                       // fp32 [N,128]
  size_t nbB = ((size_t)n * NF * sizeof(bfraw) + 255) / 256 * 256;   // bf16 blocked [8][n][16]
  float* bufA = (float*)(ws);                 // h0 / A
  float* bufB = (float*)(ws + nbF);           // h1
  bfraw* bufT = (bfraw*)(ws + 2 * nbF);       // per-layer transform out (bf16 blocked)
  bfraw* bufC = (bfraw*)(ws + 2 * nbF + nbB); // h2 (bf16 blocked)
  char* p = ws + 2 * nbF + 2 * nbB;
  int* rp = (int*)p;     p += (((size_t)(n + 1) * 4) + 255) / 256 * 256;
  int* fill = (int*)p;   p += (((size_t)n * 4) + 255) / 256 * 256;
  int* bsum = (int*)p;   p += 4096;
  unsigned* ecsr = (unsigned*)p;

  hipMemsetAsync(fill, 0, (size_t)n * 4, stream);
  int eb = (e + 255) / 256;
  int nb1 = (n + 1023) / 1024;
  count_kernel<<<eb, 256, 0, stream>>>(tgt, fill, e);
  scan1_kernel<<<nb1, 1024, 0, stream>>>(fill, rp, bsum, n);
  scan2_kernel<<<1, 1024, 0, stream>>>(bsum, nb1, &rp[n]);
  scan3_kernel<<<(n + 255) / 256, 256, 0, stream>>>(rp, fill, bsum, n);
  fill_kernel<<<8 * 256, 256, 0, stream>>>(src, tgt, mw, fill, ecsr, e, n);

  int gb = (n + 63) / 64;
  int ab = 8 * ((n + 3) / 4);   // 8 feature-blocks x node-blocks
  // L0: h0 = relu(agg(x@W0) + b0)
  gemm128_kernel<<<gb, 256, 0, stream>>>(x, W0, bufT, n);
  agg128_kernel<true, false, true, false><<<ab, 256, 0, stream>>>(
      bufT, rp, ecsr, b0, nullptr, bufA, n);
  // L1: h1 = relu(agg(h0@W1) + b1) + h0
  gemm128_kernel<<<gb, 256, 0, stream>>>(bufA, W1, bufT, n);
  agg128_kernel<true, true, true, false><<<ab, 256, 0, stream>>>(
      bufT, rp, ecsr, b1, bufA, bufB, n);
  // L2: h2 = relu(agg(h1@W2) + b2) + h1   (stored bf16 blocked)
  gemm128_kernel<<<gb, 256, 0, stream>>>(bufB, W2, bufT, n);
  agg128_kernel<true, true, true, true><<<ab, 256, 0, stream>>>(
      bufT, rp, ecsr, b2, bufB, bufC, n);
  // Final: A = agg(h2) ; out = log_softmax(A@W3 + b3)
  agg128_kernel<false, false, false, false><<<ab, 256, 0, stream>>>(
      bufC, rp, ecsr, nullptr, nullptr, bufA, n);
  gemm40_lsm_kernel<<<(n + 255) / 256, 256, 0, stream>>>(bufA, W3, b3, out, n);
}

// Round 8
// 512.449 us; speedup vs baseline: 2.7327x; 2.7327x over previous
//
#include <hip/hip_runtime.h>
#include <hip/hip_fp16.h>
#include <math.h>

#define NF 128
#define NC 40

typedef unsigned short bfraw;
typedef float f32x4 __attribute__((ext_vector_type(4)));
typedef short s16x8 __attribute__((ext_vector_type(8)));

__device__ __forceinline__ float bfLo(unsigned u) {
  return __uint_as_float(u << 16);
}
__device__ __forceinline__ float bfHi(unsigned u) {
  return __uint_as_float(u & 0xffff0000u);
}
__device__ __forceinline__ unsigned short f2bf(float f) {
  unsigned u = __float_as_uint(f);
  u += 0x7fff + ((u >> 16) & 1);  // RNE
  return (unsigned short)(u >> 16);
}
// weight in [0,1): positive fp16, 15 bits (no sign)
__device__ __forceinline__ unsigned short f2h15(float f) {
  __half h = __float2half(f);
  __half_raw hr = static_cast<__half_raw>(h);
  return (unsigned short)(hr.x & 0x7FFF);
}
__device__ __forceinline__ float h15tof(unsigned rec) {
  __half_raw hr;
  hr.x = (unsigned short)(rec & 0x7FFF);
  __half h = static_cast<__half>(hr);
  return __half2float(h);
}

// ---------------- CSR build ----------------

__global__ __launch_bounds__(256) void count_kernel(const int* __restrict__ tgt,
                                                    int* __restrict__ cnt, int e) {
  int i = blockIdx.x * 256 + threadIdx.x;
  if (i < e) atomicAdd(&cnt[__builtin_nontemporal_load(&tgt[i])], 1);
}

__global__ __launch_bounds__(1024) void scan1_kernel(const int* __restrict__ cnt,
                                                     int* __restrict__ rp,
                                                     int* __restrict__ bsum, int n) {
  __shared__ int wsum[16];
  int tid = threadIdx.x, lane = tid & 63, wid = tid >> 6;
  int i = blockIdx.x * 1024 + tid;
  int v = (i < n) ? cnt[i] : 0;
  int x = v;
  #pragma unroll
  for (int off = 1; off < 64; off <<= 1) {
    int t = __shfl_up(x, off);
    if (lane >= off) x += t;
  }
  if (lane == 63) wsum[wid] = x;
  __syncthreads();
  if (wid == 0) {
    int ws = (lane < 16) ? wsum[lane] : 0;
    int y = ws;
    #pragma unroll
    for (int off = 1; off < 16; off <<= 1) {
      int t = __shfl_up(y, off);
      if (lane >= off) y += t;
    }
    if (lane < 16) wsum[lane] = y - ws;
  }
  __syncthreads();
  int incl = x + wsum[wid];
  if (i < n) rp[i] = incl - v;
  if (tid == 1023) bsum[blockIdx.x] = incl;
}

__global__ __launch_bounds__(1024) void scan2_kernel(int* __restrict__ bsum, int nb,
                                                     int* __restrict__ rp_n) {
  __shared__ int wsum[16];
  int tid = threadIdx.x, lane = tid & 63, wid = tid >> 6;
  int v = (tid < nb) ? bsum[tid] : 0;
  int x = v;
  #pragma unroll
  for (int off = 1; off < 64; off <<= 1) {
    int t = __shfl_up(x, off);
    if (lane >= off) x += t;
  }
  if (lane == 63) wsum[wid] = x;
  __syncthreads();
  if (wid == 0) {
    int ws = (lane < 16) ? wsum[lane] : 0;
    int y = ws;
    #pragma unroll
    for (int off = 1; off < 16; off <<= 1) {
      int t = __shfl_up(y, off);
      if (lane >= off) y += t;
    }
    if (lane < 16) wsum[lane] = y - ws;
  }
  __syncthreads();
  int incl = x + wsum[wid];
  if (tid < nb) bsum[tid] = incl - v;
  if (tid == 1023) *rp_n = incl;
}

__global__ __launch_bounds__(256) void scan3_kernel(int* __restrict__ rp,
                                                    int* __restrict__ cursor,
                                                    const int* __restrict__ bsum, int n) {
  int i = blockIdx.x * 256 + threadIdx.x;
  if (i < n) {
    int v = rp[i] + bsum[i >> 10];
    rp[i] = v;
    cursor[i] = v;
  }
}

// XCD-partitioned scatter; streaming reads non-temporal.
__global__ __launch_bounds__(256) void fill_kernel(const int* __restrict__ src,
                                                   const int* __restrict__ tgt,
                                                   const float* __restrict__ mw,
                                                   int* __restrict__ cursor,
                                                   unsigned* __restrict__ ecsr,
                                                   int e, int n) {
  int part = blockIdx.x & 7;
  int nset = gridDim.x >> 3;
  int lo = (int)(((long long)n * part) >> 3);
  int hi = (int)(((long long)n * (part + 1)) >> 3);
  int stride = nset * 256;
  for (int i = (blockIdx.x >> 3) * 256 + threadIdx.x; i < e; i += stride) {
    int t = __builtin_nontemporal_load(&tgt[i]);
    if (t >= lo && t < hi) {
      int pos = atomicAdd(&cursor[t], 1);
      unsigned s = (unsigned)__builtin_nontemporal_load(&src[i]);
      float w = __builtin_nontemporal_load(&mw[i]);
      ecsr[pos] = (s << 15) | f2h15(w);
    }
  }
}

// ---------------- weight pack: W[128][128] fp32 -> B-fragment bf16 layout ----------------
// Wb[w][ct][kt][lane][j]: B elem (k = kt*32 + (lane>>4)*8 + j, col = ct*16 + (lane&15))

__global__ __launch_bounds__(256) void wpack_kernel(const float* __restrict__ W0,
                                                    const float* __restrict__ W1,
                                                    const float* __restrict__ W2,
                                                    bfraw* __restrict__ Wb) {
  int id = blockIdx.x * 256 + threadIdx.x;
  if (id >= 3 * NF * NF) return;
  int w = id >> 14;
  int el = id & 16383;
  int k = el >> 7;
  int col = el & 127;
  const float* W = (w == 0) ? W0 : ((w == 1) ? W1 : W2);
  float v = W[k * NF + col];
  int ct = col >> 4;
  int kt = k >> 5;
  int g = (k & 31) >> 3;
  int j = k & 7;
  int ln = g * 16 + (col & 15);
  Wb[((((w * 8 + ct) * 4 + kt) * 64) + ln) * 8 + j] = f2bf(v);
}

// ---------------- MFMA GEMM: Tb[n][128](bf16) = X[n][128] @ W[128][128] ----------------
// block = 256 threads (4 waves); wave computes 16 rows x 128 cols.
// A-frag: row = lane&15, k = kt*32 + (lane>>4)*8 + j (same k-map as B pack ->
// self-consistent permutation). C: col = lane&15, row = (lane>>4)*4 + reg (HW-verified).

template <bool INF32>
__global__ __launch_bounds__(256) void gemm128_mfma_kernel(const void* __restrict__ Xv,
                                                           const bfraw* __restrict__ Wb,
                                                           bfraw* __restrict__ Tb, int n) {
  __shared__ __align__(16) bfraw stage[4][16][NF + 8];
  int wv = threadIdx.x >> 6;
  int lane = threadIdx.x & 63;
  int rowBase = blockIdx.x * 64 + wv * 16;
  int arow = rowBase + (lane & 15);
  int g = lane >> 4;
  bool rv = arow < n;

  s16x8 afrag[4];
  #pragma unroll
  for (int kt = 0; kt < 4; ++kt) {
    s16x8 t = {0, 0, 0, 0, 0, 0, 0, 0};
    if (rv) {
      if (INF32) {
        const float* xr = (const float*)Xv + (size_t)arow * NF + kt * 32 + g * 8;
        float4 x0 = *(const float4*)xr;
        float4 x1 = *(const float4*)(xr + 4);
        t[0] = (short)f2bf(x0.x); t[1] = (short)f2bf(x0.y);
        t[2] = (short)f2bf(x0.z); t[3] = (short)f2bf(x0.w);
        t[4] = (short)f2bf(x1.x); t[5] = (short)f2bf(x1.y);
        t[6] = (short)f2bf(x1.z); t[7] = (short)f2bf(x1.w);
      } else {
        t = *(const s16x8*)((const bfraw*)Xv + (size_t)arow * NF + kt * 32 + g * 8);
      }
    }
    afrag[kt] = t;
  }

  #pragma unroll
  for (int ct = 0; ct < 8; ++ct) {
    f32x4 acc = {0.f, 0.f, 0.f, 0.f};
    #pragma unroll
    for (int kt = 0; kt < 4; ++kt) {
      s16x8 b = *(const s16x8*)&Wb[(((ct * 4 + kt) * 64) + lane) * 8];
      acc = __builtin_amdgcn_mfma_f32_16x16x32_bf16(afrag[kt], b, acc, 0, 0, 0);
    }
    #pragma unroll
    for (int r = 0; r < 4; ++r) {
      stage[wv][g * 4 + r][ct * 16 + (lane & 15)] = f2bf(acc[r]);
    }
  }
  __syncthreads();
  int rr = lane >> 2;
  int cc = (lane & 3) * 32;
  int grow = rowBase + rr;
  if (grow < n) {
    #pragma unroll
    for (int q = 0; q < 4; ++q) {
      uint4 v = *(const uint4*)&stage[wv][rr][cc + q * 8];
      *(uint4*)&Tb[(size_t)grow * NF + cc + q * 8] = v;
    }
  }
}

// ---------------- aggregation (pull), bf16 gather, node-major ----------------
// one wave per node; 4 edge streams x 16 lanes; lane owns 8 features (16B loads)

template <bool RELU, bool RES, bool BIAS, bool OUTBF>
__global__ __launch_bounds__(256) void agg128_kernel(const bfraw* __restrict__ Tb,
                                                     const int* __restrict__ rp,
                                                     const unsigned* __restrict__ ecsr,
                                                     const float* __restrict__ bias,
                                                     const bfraw* __restrict__ Hres,
                                                     void* __restrict__ HoutV, int n) {
  int node = (blockIdx.x * 256 + threadIdx.x) >> 6;
  int lane = threadIdx.x & 63;
  if (node >= n) return;
  int st = lane >> 4;  // edge-stream 0..3
  int fl = lane & 15;  // features 8*fl .. 8*fl+7
  int beg = rp[node], end = rp[node + 1];
  float a[8];
  #pragma unroll
  for (int i = 0; i < 8; ++i) a[i] = 0.f;
  int eidx = beg + st;
  for (; eidx + 4 < end; eidx += 8) {
    unsigned e0 = __builtin_nontemporal_load(&ecsr[eidx]);
    unsigned e1 = __builtin_nontemporal_load(&ecsr[eidx + 4]);
    float w0 = h15tof(e0);
    float w1 = h15tof(e1);
    uint4 q0 = *(const uint4*)&Tb[(size_t)(e0 >> 15) * NF + fl * 8];
    uint4 q1 = *(const uint4*)&Tb[(size_t)(e1 >> 15) * NF + fl * 8];
    a[0] = fmaf(w0, bfLo(q0.x), a[0]); a[1] = fmaf(w0, bfHi(q0.x), a[1]);
    a[2] = fmaf(w0, bfLo(q0.y), a[2]); a[3] = fmaf(w0, bfHi(q0.y), a[3]);
    a[4] = fmaf(w0, bfLo(q0.z), a[4]); a[5] = fmaf(w0, bfHi(q0.z), a[5]);
    a[6] = fmaf(w0, bfLo(q0.w), a[6]); a[7] = fmaf(w0, bfHi(q0.w), a[7]);
    a[0] = fmaf(w1, bfLo(q1.x), a[0]); a[1] = fmaf(w1, bfHi(q1.x), a[1]);
    a[2] = fmaf(w1, bfLo(q1.y), a[2]); a[3] = fmaf(w1, bfHi(q1.y), a[3]);
    a[4] = fmaf(w1, bfLo(q1.z), a[4]); a[5] = fmaf(w1, bfHi(q1.z), a[5]);
    a[6] = fmaf(w1, bfLo(q1.w), a[6]); a[7] = fmaf(w1, bfHi(q1.w), a[7]);
  }
  if (eidx < end) {
    unsigned e0 = __builtin_nontemporal_load(&ecsr[eidx]);
    float w0 = h15tof(e0);
    uint4 q0 = *(const uint4*)&Tb[(size_t)(e0 >> 15) * NF + fl * 8];
    a[0] = fmaf(w0, bfLo(q0.x), a[0]); a[1] = fmaf(w0, bfHi(q0.x), a[1]);
    a[2] = fmaf(w0, bfLo(q0.y), a[2]); a[3] = fmaf(w0, bfHi(q0.y), a[3]);
    a[4] = fmaf(w0, bfLo(q0.z), a[4]); a[5] = fmaf(w0, bfHi(q0.z), a[5]);
    a[6] = fmaf(w0, bfLo(q0.w), a[6]); a[7] = fmaf(w0, bfHi(q0.w), a[7]);
  }
  #pragma unroll
  for (int i = 0; i < 8; ++i) {
    a[i] += __shfl_xor(a[i], 16);
    a[i] += __shfl_xor(a[i], 32);
  }
  if (st == 0) {
    if (BIAS) {
      float4 b0 = *(const float4*)&bias[fl * 8];
      float4 b1 = *(const float4*)&bias[fl * 8 + 4];
      a[0] += b0.x; a[1] += b0.y; a[2] += b0.z; a[3] += b0.w;
      a[4] += b1.x; a[5] += b1.y; a[6] += b1.z; a[7] += b1.w;
    }
    if (RELU) {
      #pragma unroll
      for (int i = 0; i < 8; ++i) a[i] = fmaxf(a[i], 0.f);
    }
    if (RES) {
      uint4 r = *(const uint4*)&Hres[(size_t)node * NF + fl * 8];
      a[0] += bfLo(r.x); a[1] += bfHi(r.x);
      a[2] += bfLo(r.y); a[3] += bfHi(r.y);
      a[4] += bfLo(r.z); a[5] += bfHi(r.z);
      a[6] += bfLo(r.w); a[7] += bfHi(r.w);
    }
    if (OUTBF) {
      bfraw* Hout = (bfraw*)HoutV;
      uint4 o;
      o.x = ((unsigned)f2bf(a[1]) << 16) | f2bf(a[0]);
      o.y = ((unsigned)f2bf(a[3]) << 16) | f2bf(a[2]);
      o.z = ((unsigned)f2bf(a[5]) << 16) | f2bf(a[4]);
      o.w = ((unsigned)f2bf(a[7]) << 16) | f2bf(a[6]);
      *(uint4*)&Hout[(size_t)node * NF + fl * 8] = o;
    } else {
      float* Hout = (float*)HoutV;
      float4 o0, o1;
      o0.x = a[0]; o0.y = a[1]; o0.z = a[2]; o0.w = a[3];
      o1.x = a[4]; o1.y = a[5]; o1.z = a[6]; o1.w = a[7];
      *(float4*)&Hout[(size_t)node * NF + fl * 8] = o0;
      *(float4*)&Hout[(size_t)node * NF + fl * 8 + 4] = o1;
    }
  }
}

// ---------------- fused final: out = log_softmax(A@W3 + b3) ----------------

__global__ __launch_bounds__(256) void gemm40_lsm_kernel(const float* __restrict__ A,
                                                         const float* __restrict__ W,
                                                         const float* __restrict__ bias,
                                                         float* __restrict__ out, int n) {
  __shared__ float Ws[NF * NC];  // 20 KB
  int tid = threadIdx.x;
  #pragma unroll
  for (int it = 0; it < 5; ++it) {
    int off = it * 1024 + tid * 4;
    *(float4*)&Ws[off] = *(const float4*)&W[off];
  }
  __syncthreads();
  int node = blockIdx.x * 256 + tid;
  if (node >= n) return;

  float4 acc[10];
  #pragma unroll
  for (int cg = 0; cg < 10; ++cg) acc[cg] = *(const float4*)&bias[cg * 4];

  const float* arow = A + (size_t)node * NF;
  for (int k0 = 0; k0 < NF; k0 += 4) {
    float4 a4 = *(const float4*)&arow[k0];
    float av[4] = {a4.x, a4.y, a4.z, a4.w};
    #pragma unroll
    for (int j = 0; j < 4; ++j) {
      #pragma unroll
      for (int cg = 0; cg < 10; ++cg) {
        float4 w4 = *(const float4*)&Ws[(k0 + j) * NC + cg * 4];
        acc[cg].x = fmaf(av[j], w4.x, acc[cg].x);
        acc[cg].y = fmaf(av[j], w4.y, acc[cg].y);
        acc[cg].z = fmaf(av[j], w4.z, acc[cg].z);
        acc[cg].w = fmaf(av[j], w4.w, acc[cg].w);
      }
    }
  }
  float m = -INFINITY;
  #pragma unroll
  for (int cg = 0; cg < 10; ++cg) {
    m = fmaxf(m, fmaxf(fmaxf(acc[cg].x, acc[cg].y), fmaxf(acc[cg].z, acc[cg].w)));
  }
  float s = 0.f;
  #pragma unroll
  for (int cg = 0; cg < 10; ++cg) {
    s += expf(acc[cg].x - m) + expf(acc[cg].y - m) +
         expf(acc[cg].z - m) + expf(acc[cg].w - m);
  }
  float lse = m + logf(s);
  float* orow = out + (size_t)node * NC;
  #pragma unroll
  for (int cg = 0; cg < 10; ++cg) {
    float4 o;
    o.x = acc[cg].x - lse; o.y = acc[cg].y - lse;
    o.z = acc[cg].z - lse; o.w = acc[cg].w - lse;
    *(float4*)&orow[cg * 4] = o;
  }
}

// ---------------- launch ----------------

extern "C" void kernel_launch(void* const* d_in, const int* in_sizes, int n_in,
                              void* d_out, int out_size, void* d_ws, size_t ws_size,
                              hipStream_t stream) {
  const float* x   = (const float*)d_in[0];
  const int*   src = (const int*)d_in[1];
  const int*   tgt = (const int*)d_in[2];
  const float* mw  = (const float*)d_in[3];
  const float* W0  = (const float*)d_in[4];
  const float* b0  = (const float*)d_in[5];
  const float* W1  = (const float*)d_in[6];
  const float* b1  = (const float*)d_in[7];
  const float* W2  = (const float*)d_in[8];
  const float* b2  = (const float*)d_in[9];
  const float* W3  = (const float*)d_in[10];
  const float* b3  = (const float*)d_in[11];
  int n = in_sizes[0] / NF;
  int e = in_sizes[1];
  float* out = (float*)d_out;

  char* ws = (char*)d_ws;
  size_t nbF = (size_t)n * NF * sizeof(float);                       // fp32 [N,128]
  size_t nbB = (((size_t)n * NF * sizeof(bfraw)) + 255) / 256 * 256; // bf16 [N,128]
  float* bufA  = (float*)(ws);                   // final A (fp32)
  bfraw* bufT  = (bfraw*)(ws + nbF);             // transform out (bf16)
  bfraw* bufH0 = (bfraw*)(ws + nbF + nbB);       // h0 / h2
  bfraw* bufH1 = (bfraw*)(ws + nbF + 2 * nbB);   // h1
  char* p = ws + nbF + 3 * nbB;
  bfraw* Wb = (bfraw*)p;  p += ((3 * 8 * 4 * 64 * 8 * sizeof(bfraw)) + 255) / 256 * 256;
  int* rp = (int*)p;      p += (((size_t)(n + 1) * 4) + 255) / 256 * 256;
  int* fill = (int*)p;    p += (((size_t)n * 4) + 255) / 256 * 256;
  int* bsum = (int*)p;    p += 4096;
  unsigned* ecsr = (unsigned*)p;

  hipMemsetAsync(fill, 0, (size_t)n * 4, stream);
  int eb = (e + 255) / 256;
  int nb1 = (n + 1023) / 1024;
  count_kernel<<<eb, 256, 0, stream>>>(tgt, fill, e);
  scan1_kernel<<<nb1, 1024, 0, stream>>>(fill, rp, bsum, n);
  scan2_kernel<<<1, 1024, 0, stream>>>(bsum, nb1, &rp[n]);
  scan3_kernel<<<(n + 255) / 256, 256, 0, stream>>>(rp, fill, bsum, n);
  fill_kernel<<<8 * 256, 256, 0, stream>>>(src, tgt, mw, fill, ecsr, e, n);
  wpack_kernel<<<(3 * NF * NF + 255) / 256, 256, 0, stream>>>(W0, W1, W2, Wb);

  int gb = (n + 63) / 64;
  int ab = (n + 3) / 4;
  // L0: h0 = relu(agg(x@W0) + b0)                       (h0 bf16)
  gemm128_mfma_kernel<true><<<gb, 256, 0, stream>>>(x, Wb, bufT, n);
  agg128_kernel<true, false, true, true><<<ab, 256, 0, stream>>>(
      bufT, rp, ecsr, b0, nullptr, bufH0, n);
  // L1: h1 = relu(agg(h0@W1) + b1) + h0                 (h1 bf16)
  gemm128_mfma_kernel<false><<<gb, 256, 0, stream>>>(bufH0, Wb + 8 * 4 * 64 * 8, bufT, n);
  agg128_kernel<true, true, true, true><<<ab, 256, 0, stream>>>(
      bufT, rp, ecsr, b1, bufH0, bufH1, n);
  // L2: h2 = relu(agg(h1@W2) + b2) + h1                 (h2 bf16, reuses h0 buf)
  gemm128_mfma_kernel<false><<<gb, 256, 0, stream>>>(bufH1, Wb + 2 * 8 * 4 * 64 * 8, bufT, n);
  agg128_kernel<true, true, true, true><<<ab, 256, 0, stream>>>(
      bufT, rp, ecsr, b2, bufH1, bufH0, n);
  // Final: A = agg(h2) (fp32) ; out = log_softmax(A@W3 + b3)
  agg128_kernel<false, false, false, false><<<ab, 256, 0, stream>>>(
      bufH0, rp, ecsr, nullptr, nullptr, bufA, n);
  gemm40_lsm_kernel<<<(n + 255) / 256, 256, 0, stream>>>(bufA, W3, b3, out, n);
}

// Round 9
// 488.517 us; speedup vs baseline: 2.8666x; 1.0490x over previous
//
#include <hip/hip_runtime.h>
#include <hip/hip_fp16.h>
#include <math.h>

#define NF 128
#define NC 40

typedef unsigned short bfraw;
typedef float f32x4 __attribute__((ext_vector_type(4)));
typedef short s16x8 __attribute__((ext_vector_type(8)));

__device__ __forceinline__ float bfLo(unsigned u) {
  return __uint_as_float(u << 16);
}
__device__ __forceinline__ float bfHi(unsigned u) {
  return __uint_as_float(u & 0xffff0000u);
}
__device__ __forceinline__ unsigned short f2bf(float f) {
  unsigned u = __float_as_uint(f);
  u += 0x7fff + ((u >> 16) & 1);  // RNE
  return (unsigned short)(u >> 16);
}
// weight in [0,1): positive fp16, 15 bits (no sign)
__device__ __forceinline__ unsigned short f2h15(float f) {
  __half h = __float2half(f);
  __half_raw hr = static_cast<__half_raw>(h);
  return (unsigned short)(hr.x & 0x7FFF);
}
__device__ __forceinline__ float h15tof(unsigned rec) {
  __half_raw hr;
  hr.x = (unsigned short)(rec & 0x7FFF);
  __half h = static_cast<__half>(hr);
  return __half2float(h);
}

// ---------------- CSR build ----------------

__global__ __launch_bounds__(256) void count_kernel(const int* __restrict__ tgt,
                                                    int* __restrict__ cnt, int e) {
  int i = blockIdx.x * 256 + threadIdx.x;
  if (i < e) atomicAdd(&cnt[__builtin_nontemporal_load(&tgt[i])], 1);
}

__global__ __launch_bounds__(1024) void scan1_kernel(const int* __restrict__ cnt,
                                                     int* __restrict__ rp,
                                                     int* __restrict__ bsum, int n) {
  __shared__ int wsum[16];
  int tid = threadIdx.x, lane = tid & 63, wid = tid >> 6;
  int i = blockIdx.x * 1024 + tid;
  int v = (i < n) ? cnt[i] : 0;
  int x = v;
  #pragma unroll
  for (int off = 1; off < 64; off <<= 1) {
    int t = __shfl_up(x, off);
    if (lane >= off) x += t;
  }
  if (lane == 63) wsum[wid] = x;
  __syncthreads();
  if (wid == 0) {
    int ws = (lane < 16) ? wsum[lane] : 0;
    int y = ws;
    #pragma unroll
    for (int off = 1; off < 16; off <<= 1) {
      int t = __shfl_up(y, off);
      if (lane >= off) y += t;
    }
    if (lane < 16) wsum[lane] = y - ws;
  }
  __syncthreads();
  int incl = x + wsum[wid];
  if (i < n) rp[i] = incl - v;
  if (tid == 1023) bsum[blockIdx.x] = incl;
}

__global__ __launch_bounds__(1024) void scan2_kernel(int* __restrict__ bsum, int nb,
                                                     int* __restrict__ rp_n) {
  __shared__ int wsum[16];
  int tid = threadIdx.x, lane = tid & 63, wid = tid >> 6;
  int v = (tid < nb) ? bsum[tid] : 0;
  int x = v;
  #pragma unroll
  for (int off = 1; off < 64; off <<= 1) {
    int t = __shfl_up(x, off);
    if (lane >= off) x += t;
  }
  if (lane == 63) wsum[wid] = x;
  __syncthreads();
  if (wid == 0) {
    int ws = (lane < 16) ? wsum[lane] : 0;
    int y = ws;
    #pragma unroll
    for (int off = 1; off < 16; off <<= 1) {
      int t = __shfl_up(y, off);
      if (lane >= off) y += t;
    }
    if (lane < 16) wsum[lane] = y - ws;
  }
  __syncthreads();
  int incl = x + wsum[wid];
  if (tid < nb) bsum[tid] = incl - v;
  if (tid == 1023) *rp_n = incl;
}

__global__ __launch_bounds__(256) void scan3_kernel(int* __restrict__ rp,
                                                    int* __restrict__ cursor,
                                                    const int* __restrict__ bsum, int n) {
  int i = blockIdx.x * 256 + threadIdx.x;
  if (i < n) {
    int v = rp[i] + bsum[i >> 10];
    rp[i] = v;
    cursor[i] = v;
  }
}

// XCD-partitioned scatter; streaming reads non-temporal.
__global__ __launch_bounds__(256) void fill_kernel(const int* __restrict__ src,
                                                   const int* __restrict__ tgt,
                                                   const float* __restrict__ mw,
                                                   int* __restrict__ cursor,
                                                   unsigned* __restrict__ ecsr,
                                                   int e, int n) {
  int part = blockIdx.x & 7;
  int nset = gridDim.x >> 3;
  int lo = (int)(((long long)n * part) >> 3);
  int hi = (int)(((long long)n * (part + 1)) >> 3);
  int stride = nset * 256;
  for (int i = (blockIdx.x >> 3) * 256 + threadIdx.x; i < e; i += stride) {
    int t = __builtin_nontemporal_load(&tgt[i]);
    if (t >= lo && t < hi) {
      int pos = atomicAdd(&cursor[t], 1);
      unsigned s = (unsigned)__builtin_nontemporal_load(&src[i]);
      float w = __builtin_nontemporal_load(&mw[i]);
      ecsr[pos] = (s << 15) | f2h15(w);
    }
  }
}

// ---------------- weight pack: W[128][128] fp32 -> B-fragment bf16 layout ----------------
// Wb[w][ct][kt][lane][j]: B elem (k = kt*32 + (lane>>4)*8 + j, col = ct*16 + (lane&15))

__global__ __launch_bounds__(256) void wpack_kernel(const float* __restrict__ W0,
                                                    const float* __restrict__ W1,
                                                    const float* __restrict__ W2,
                                                    bfraw* __restrict__ Wb) {
  int id = blockIdx.x * 256 + threadIdx.x;
  if (id >= 3 * NF * NF) return;
  int w = id >> 14;
  int el = id & 16383;
  int k = el >> 7;
  int col = el & 127;
  const float* W = (w == 0) ? W0 : ((w == 1) ? W1 : W2);
  float v = W[k * NF + col];
  int ct = col >> 4;
  int kt = k >> 5;
  int g = (k & 31) >> 3;
  int j = k & 7;
  int ln = g * 16 + (col & 15);
  Wb[((((w * 8 + ct) * 4 + kt) * 64) + ln) * 8 + j] = f2bf(v);
}

// W3[128][40] fp32 -> B-frag layout over 48 cols (cols 40..47 zero)
__global__ __launch_bounds__(256) void wpack40_kernel(const float* __restrict__ W3,
                                                      bfraw* __restrict__ Wb3) {
  int id = blockIdx.x * 256 + threadIdx.x;
  if (id >= NF * 48) return;
  int k = id / 48;
  int col = id % 48;
  float v = (col < NC) ? W3[k * NC + col] : 0.f;
  int ct = col >> 4;
  int kt = k >> 5;
  int g = (k & 31) >> 3;
  int j = k & 7;
  int ln = g * 16 + (col & 15);
  Wb3[(((ct * 4 + kt) * 64) + ln) * 8 + j] = f2bf(v);
}

// ---------------- MFMA GEMM: Tb[n][128](bf16) = X[n][128] @ W[128][128] ----------------

template <bool INF32>
__global__ __launch_bounds__(256) void gemm128_mfma_kernel(const void* __restrict__ Xv,
                                                           const bfraw* __restrict__ Wb,
                                                           bfraw* __restrict__ Tb, int n) {
  __shared__ __align__(16) bfraw stage[4][16][NF + 8];
  int wv = threadIdx.x >> 6;
  int lane = threadIdx.x & 63;
  int rowBase = blockIdx.x * 64 + wv * 16;
  int arow = rowBase + (lane & 15);
  int g = lane >> 4;
  bool rv = arow < n;

  s16x8 afrag[4];
  #pragma unroll
  for (int kt = 0; kt < 4; ++kt) {
    s16x8 t = {0, 0, 0, 0, 0, 0, 0, 0};
    if (rv) {
      if (INF32) {
        const float* xr = (const float*)Xv + (size_t)arow * NF + kt * 32 + g * 8;
        float4 x0 = *(const float4*)xr;
        float4 x1 = *(const float4*)(xr + 4);
        t[0] = (short)f2bf(x0.x); t[1] = (short)f2bf(x0.y);
        t[2] = (short)f2bf(x0.z); t[3] = (short)f2bf(x0.w);
        t[4] = (short)f2bf(x1.x); t[5] = (short)f2bf(x1.y);
        t[6] = (short)f2bf(x1.z); t[7] = (short)f2bf(x1.w);
      } else {
        t = *(const s16x8*)((const bfraw*)Xv + (size_t)arow * NF + kt * 32 + g * 8);
      }
    }
    afrag[kt] = t;
  }

  #pragma unroll
  for (int ct = 0; ct < 8; ++ct) {
    f32x4 acc = {0.f, 0.f, 0.f, 0.f};
    #pragma unroll
    for (int kt = 0; kt < 4; ++kt) {
      s16x8 b = *(const s16x8*)&Wb[(((ct * 4 + kt) * 64) + lane) * 8];
      acc = __builtin_amdgcn_mfma_f32_16x16x32_bf16(afrag[kt], b, acc, 0, 0, 0);
    }
    #pragma unroll
    for (int r = 0; r < 4; ++r) {
      stage[wv][g * 4 + r][ct * 16 + (lane & 15)] = f2bf(acc[r]);
    }
  }
  __syncthreads();
  int rr = lane >> 2;
  int cc = (lane & 3) * 32;
  int grow = rowBase + rr;
  if (grow < n) {
    #pragma unroll
    for (int q = 0; q < 4; ++q) {
      uint4 v = *(const uint4*)&stage[wv][rr][cc + q * 8];
      *(uint4*)&Tb[(size_t)grow * NF + cc + q * 8] = v;
    }
  }
}

// ---------------- MFMA GEMM: T40[n][64](bf16) = h2[n][128] @ W3pad[128][48] ----------------
// cols 40..63 exact zeros (zero-padded W3 pack + zeroed stage cols 48..63).

__global__ __launch_bounds__(256) void gemm40_mfma_kernel(const bfraw* __restrict__ X,
                                                          const bfraw* __restrict__ Wb3,
                                                          bfraw* __restrict__ T40, int n) {
  __shared__ __align__(16) bfraw stage[4][16][72];
  int wv = threadIdx.x >> 6;
  int lane = threadIdx.x & 63;
  int rowBase = blockIdx.x * 64 + wv * 16;
  int arow = rowBase + (lane & 15);
  int g = lane >> 4;
  bool rv = arow < n;

  s16x8 afrag[4];
  #pragma unroll
  for (int kt = 0; kt < 4; ++kt) {
    s16x8 t = {0, 0, 0, 0, 0, 0, 0, 0};
    if (rv) t = *(const s16x8*)&X[(size_t)arow * NF + kt * 32 + g * 8];
    afrag[kt] = t;
  }

  #pragma unroll
  for (int ct = 0; ct < 3; ++ct) {
    f32x4 acc = {0.f, 0.f, 0.f, 0.f};
    #pragma unroll
    for (int kt = 0; kt < 4; ++kt) {
      s16x8 b = *(const s16x8*)&Wb3[(((ct * 4 + kt) * 64) + lane) * 8];
      acc = __builtin_amdgcn_mfma_f32_16x16x32_bf16(afrag[kt], b, acc, 0, 0, 0);
    }
    #pragma unroll
    for (int r = 0; r < 4; ++r) {
      stage[wv][g * 4 + r][ct * 16 + (lane & 15)] = f2bf(acc[r]);
    }
  }
  // zero cols 48..63
  #pragma unroll
  for (int r = 0; r < 4; ++r) stage[wv][g * 4 + r][48 + (lane & 15)] = 0;
  __syncthreads();
  int rr = lane >> 2;
  int cc = (lane & 3) * 16;
  int grow = rowBase + rr;
  if (grow < n) {
    uint4 v0 = *(const uint4*)&stage[wv][rr][cc];
    uint4 v1 = *(const uint4*)&stage[wv][rr][cc + 8];
    *(uint4*)&T40[(size_t)grow * 64 + cc] = v0;
    *(uint4*)&T40[(size_t)grow * 64 + cc + 8] = v1;
  }
}

// ---------------- aggregation (pull), bf16 gather, node-major, 128 feats ----------------

template <bool RELU, bool RES, bool BIAS, bool OUTBF>
__global__ __launch_bounds__(256) void agg128_kernel(const bfraw* __restrict__ Tb,
                                                     const int* __restrict__ rp,
                                                     const unsigned* __restrict__ ecsr,
                                                     const float* __restrict__ bias,
                                                     const bfraw* __restrict__ Hres,
                                                     void* __restrict__ HoutV, int n) {
  int node = (blockIdx.x * 256 + threadIdx.x) >> 6;
  int lane = threadIdx.x & 63;
  if (node >= n) return;
  int st = lane >> 4;  // edge-stream 0..3
  int fl = lane & 15;  // features 8*fl .. 8*fl+7
  int beg = rp[node], end = rp[node + 1];
  float a[8];
  #pragma unroll
  for (int i = 0; i < 8; ++i) a[i] = 0.f;
  int eidx = beg + st;
  for (; eidx + 4 < end; eidx += 8) {
    unsigned e0 = __builtin_nontemporal_load(&ecsr[eidx]);
    unsigned e1 = __builtin_nontemporal_load(&ecsr[eidx + 4]);
    float w0 = h15tof(e0);
    float w1 = h15tof(e1);
    uint4 q0 = *(const uint4*)&Tb[(size_t)(e0 >> 15) * NF + fl * 8];
    uint4 q1 = *(const uint4*)&Tb[(size_t)(e1 >> 15) * NF + fl * 8];
    a[0] = fmaf(w0, bfLo(q0.x), a[0]); a[1] = fmaf(w0, bfHi(q0.x), a[1]);
    a[2] = fmaf(w0, bfLo(q0.y), a[2]); a[3] = fmaf(w0, bfHi(q0.y), a[3]);
    a[4] = fmaf(w0, bfLo(q0.z), a[4]); a[5] = fmaf(w0, bfHi(q0.z), a[5]);
    a[6] = fmaf(w0, bfLo(q0.w), a[6]); a[7] = fmaf(w0, bfHi(q0.w), a[7]);
    a[0] = fmaf(w1, bfLo(q1.x), a[0]); a[1] = fmaf(w1, bfHi(q1.x), a[1]);
    a[2] = fmaf(w1, bfLo(q1.y), a[2]); a[3] = fmaf(w1, bfHi(q1.y), a[3]);
    a[4] = fmaf(w1, bfLo(q1.z), a[4]); a[5] = fmaf(w1, bfHi(q1.z), a[5]);
    a[6] = fmaf(w1, bfLo(q1.w), a[6]); a[7] = fmaf(w1, bfHi(q1.w), a[7]);
  }
  if (eidx < end) {
    unsigned e0 = __builtin_nontemporal_load(&ecsr[eidx]);
    float w0 = h15tof(e0);
    uint4 q0 = *(const uint4*)&Tb[(size_t)(e0 >> 15) * NF + fl * 8];
    a[0] = fmaf(w0, bfLo(q0.x), a[0]); a[1] = fmaf(w0, bfHi(q0.x), a[1]);
    a[2] = fmaf(w0, bfLo(q0.y), a[2]); a[3] = fmaf(w0, bfHi(q0.y), a[3]);
    a[4] = fmaf(w0, bfLo(q0.z), a[4]); a[5] = fmaf(w0, bfHi(q0.z), a[5]);
    a[6] = fmaf(w0, bfLo(q0.w), a[6]); a[7] = fmaf(w0, bfHi(q0.w), a[7]);
  }
  #pragma unroll
  for (int i = 0; i < 8; ++i) {
    a[i] += __shfl_xor(a[i], 16);
    a[i] += __shfl_xor(a[i], 32);
  }
  if (st == 0) {
    if (BIAS) {
      float4 b0 = *(const float4*)&bias[fl * 8];
      float4 b1 = *(const float4*)&bias[fl * 8 + 4];
      a[0] += b0.x; a[1] += b0.y; a[2] += b0.z; a[3] += b0.w;
      a[4] += b1.x; a[5] += b1.y; a[6] += b1.z; a[7] += b1.w;
    }
    if (RELU) {
      #pragma unroll
      for (int i = 0; i < 8; ++i) a[i] = fmaxf(a[i], 0.f);
    }
    if (RES) {
      uint4 r = *(const uint4*)&Hres[(size_t)node * NF + fl * 8];
      a[0] += bfLo(r.x); a[1] += bfHi(r.x);
      a[2] += bfLo(r.y); a[3] += bfHi(r.y);
      a[4] += bfLo(r.z); a[5] += bfHi(r.z);
      a[6] += bfLo(r.w); a[7] += bfHi(r.w);
    }
    if (OUTBF) {
      bfraw* Hout = (bfraw*)HoutV;
      uint4 o;
      o.x = ((unsigned)f2bf(a[1]) << 16) | f2bf(a[0]);
      o.y = ((unsigned)f2bf(a[3]) << 16) | f2bf(a[2]);
      o.z = ((unsigned)f2bf(a[5]) << 16) | f2bf(a[4]);
      o.w = ((unsigned)f2bf(a[7]) << 16) | f2bf(a[6]);
      *(uint4*)&Hout[(size_t)node * NF + fl * 8] = o;
    } else {
      float* Hout = (float*)HoutV;
      float4 o0, o1;
      o0.x = a[0]; o0.y = a[1]; o0.z = a[2]; o0.w = a[3];
      o1.x = a[4]; o1.y = a[5]; o1.z = a[6]; o1.w = a[7];
      *(float4*)&Hout[(size_t)node * NF + fl * 8] = o0;
      *(float4*)&Hout[(size_t)node * NF + fl * 8 + 4] = o1;
    }
  }
}

// ---------------- final: out = log_softmax(agg40(T40) + b3) ----------------
// one wave per node; 4 edge streams x 16 lanes; lane owns 4 cols (8 B loads);
// cols >= 40 are exact zeros -> lanes fl >= 10 discarded.

__global__ __launch_bounds__(256) void agg40_lsm_kernel(const bfraw* __restrict__ T40,
                                                        const int* __restrict__ rp,
                                                        const unsigned* __restrict__ ecsr,
                                                        const float* __restrict__ bias,
                                                        float* __restrict__ out, int n) {
  int node = (blockIdx.x * 256 + threadIdx.x) >> 6;
  int lane = threadIdx.x & 63;
  if (node >= n) return;
  int st = lane >> 4;  // edge-stream 0..3
  int fl = lane & 15;  // cols 4*fl .. 4*fl+3
  int beg = rp[node], end = rp[node + 1];
  float a0 = 0.f, a1 = 0.f, a2 = 0.f, a3 = 0.f;
  int eidx = beg + st;
  for (; eidx + 4 < end; eidx += 8) {
    unsigned e0 = __builtin_nontemporal_load(&ecsr[eidx]);
    unsigned e1 = __builtin_nontemporal_load(&ecsr[eidx + 4]);
    float w0 = h15tof(e0);
    float w1 = h15tof(e1);
    uint2 q0 = *(const uint2*)&T40[(size_t)(e0 >> 15) * 64 + fl * 4];
    uint2 q1 = *(const uint2*)&T40[(size_t)(e1 >> 15) * 64 + fl * 4];
    a0 = fmaf(w0, bfLo(q0.x), a0); a1 = fmaf(w0, bfHi(q0.x), a1);
    a2 = fmaf(w0, bfLo(q0.y), a2); a3 = fmaf(w0, bfHi(q0.y), a3);
    a0 = fmaf(w1, bfLo(q1.x), a0); a1 = fmaf(w1, bfHi(q1.x), a1);
    a2 = fmaf(w1, bfLo(q1.y), a2); a3 = fmaf(w1, bfHi(q1.y), a3);
  }
  if (eidx < end) {
    unsigned e0 = __builtin_nontemporal_load(&ecsr[eidx]);
    float w0 = h15tof(e0);
    uint2 q0 = *(const uint2*)&T40[(size_t)(e0 >> 15) * 64 + fl * 4];
    a0 = fmaf(w0, bfLo(q0.x), a0); a1 = fmaf(w0, bfHi(q0.x), a1);
    a2 = fmaf(w0, bfLo(q0.y), a2); a3 = fmaf(w0, bfHi(q0.y), a3);
  }
  a0 += __shfl_xor(a0, 16); a0 += __shfl_xor(a0, 32);
  a1 += __shfl_xor(a1, 16); a1 += __shfl_xor(a1, 32);
  a2 += __shfl_xor(a2, 16); a2 += __shfl_xor(a2, 32);
  a3 += __shfl_xor(a3, 16); a3 += __shfl_xor(a3, 32);
  if (st == 0) {
    bool v = fl < 10;
    if (v) {
      float4 b = *(const float4*)&bias[fl * 4];
      a0 += b.x; a1 += b.y; a2 += b.z; a3 += b.w;
    }
    float lm = v ? fmaxf(fmaxf(a0, a1), fmaxf(a2, a3)) : -INFINITY;
    #pragma unroll
    for (int off = 1; off < 16; off <<= 1) lm = fmaxf(lm, __shfl_xor(lm, off));
    float ls = v ? (expf(a0 - lm) + expf(a1 - lm) + expf(a2 - lm) + expf(a3 - lm)) : 0.f;
    #pragma unroll
    for (int off = 1; off < 16; off <<= 1) ls += __shfl_xor(ls, off);
    float lse = lm + logf(ls);
    if (v) {
      float4 o;
      o.x = a0 - lse; o.y = a1 - lse; o.z = a2 - lse; o.w = a3 - lse;
      *(float4*)&out[(size_t)node * NC + fl * 4] = o;
    }
  }
}

// ---------------- launch ----------------

extern "C" void kernel_launch(void* const* d_in, const int* in_sizes, int n_in,
                              void* d_out, int out_size, void* d_ws, size_t ws_size,
                              hipStream_t stream) {
  const float* x   = (const float*)d_in[0];
  const int*   src = (const int*)d_in[1];
  const int*   tgt = (const int*)d_in[2];
  const float* mw  = (const float*)d_in[3];
  const float* W0  = (const float*)d_in[4];
  const float* b0  = (const float*)d_in[5];
  const float* W1  = (const float*)d_in[6];
  const float* b1  = (const float*)d_in[7];
  const float* W2  = (const float*)d_in[8];
  const float* b2  = (const float*)d_in[9];
  const float* W3  = (const float*)d_in[10];
  const float* b3  = (const float*)d_in[11];
  int n = in_sizes[0] / NF;
  int e = in_sizes[1];
  float* out = (float*)d_out;

  char* ws = (char*)d_ws;
  size_t nbB = (((size_t)n * NF * sizeof(bfraw)) + 255) / 256 * 256; // bf16 [N,128]
  bfraw* bufT  = (bfraw*)(ws);                   // transform out (bf16), also T40 (stride 64)
  bfraw* bufH0 = (bfraw*)(ws + nbB);             // h0 / h2
  bfraw* bufH1 = (bfraw*)(ws + 2 * nbB);         // h1
  char* p = ws + 3 * nbB;
  bfraw* Wb = (bfraw*)p;   // 3 gemm128 packs + 1 gemm40 pack
  p += (((3 * 8 + 3) * 4 * 64 * 8 * sizeof(bfraw)) + 255) / 256 * 256;
  int* rp = (int*)p;      p += (((size_t)(n + 1) * 4) + 255) / 256 * 256;
  int* fill = (int*)p;    p += (((size_t)n * 4) + 255) / 256 * 256;
  int* bsum = (int*)p;    p += 4096;
  unsigned* ecsr = (unsigned*)p;

  bfraw* Wb3 = Wb + 3 * 8 * 4 * 64 * 8;

  hipMemsetAsync(fill, 0, (size_t)n * 4, stream);
  int eb = (e + 255) / 256;
  int nb1 = (n + 1023) / 1024;
  count_kernel<<<eb, 256, 0, stream>>>(tgt, fill, e);
  scan1_kernel<<<nb1, 1024, 0, stream>>>(fill, rp, bsum, n);
  scan2_kernel<<<1, 1024, 0, stream>>>(bsum, nb1, &rp[n]);
  scan3_kernel<<<(n + 255) / 256, 256, 0, stream>>>(rp, fill, bsum, n);
  fill_kernel<<<8 * 256, 256, 0, stream>>>(src, tgt, mw, fill, ecsr, e, n);
  wpack_kernel<<<(3 * NF * NF + 255) / 256, 256, 0, stream>>>(W0, W1, W2, Wb);
  wpack40_kernel<<<(NF * 48 + 255) / 256, 256, 0, stream>>>(W3, Wb3);

  int gb = (n + 63) / 64;
  int ab = (n + 3) / 4;
  // L0: h0 = relu(agg(x@W0) + b0)                       (h0 bf16)
  gemm128_mfma_kernel<true><<<gb, 256, 0, stream>>>(x, Wb, bufT, n);
  agg128_kernel<true, false, true, true><<<ab, 256, 0, stream>>>(
      bufT, rp, ecsr, b0, nullptr, bufH0, n);
  // L1: h1 = relu(agg(h0@W1) + b1) + h0                 (h1 bf16)
  gemm128_mfma_kernel<false><<<gb, 256, 0, stream>>>(bufH0, Wb + 8 * 4 * 64 * 8, bufT, n);
  agg128_kernel<true, true, true, true><<<ab, 256, 0, stream>>>(
      bufT, rp, ecsr, b1, bufH0, bufH1, n);
  // L2: h2 = relu(agg(h1@W2) + b2) + h1                 (h2 bf16, reuses h0 buf)
  gemm128_mfma_kernel<false><<<gb, 256, 0, stream>>>(bufH1, Wb + 2 * 8 * 4 * 64 * 8, bufT, n);
  agg128_kernel<true, true, true, true><<<ab, 256, 0, stream>>>(
      bufT, rp, ecsr, b2, bufH1, bufH0, n);
  // Final: T40 = h2 @ W3pad (bf16, stride 64) ; out = log_softmax(agg40(T40) + b3)
  gemm40_mfma_kernel<<<gb, 256, 0, stream>>>(bufH0, Wb3, bufT, n);
  agg40_lsm_kernel<<<ab, 256, 0, stream>>>(bufT, rp, ecsr, b3, out, n);
}